// Round 9
// baseline (39.292 us; speedup 1.0000x reference)
//
#include <hip/hip_runtime.h>

#define EPSF 1e-20f

constexpr int Hh = 768, Ww = 768, Bb = 4;
constexpr int PLANE = Hh * Ww;
constexpr int TS = 32;         // output tile
constexpr int R3 = TS + 6;     // 38: halo-3 (dq, c)
constexpr int R2 = TS + 4;     // 36: halo-2 (tc, ts)
constexpr int R1 = TS + 2;     // 34: halo-1 (s)

// fused: stage 1 (hierarchical argmax) + stage 2 (conv, split interior/ring) + stage 3
__global__ __launch_bounds__(256)
void fused_all(const float* __restrict__ x, const float* __restrict__ scs,
               const float* __restrict__ cs,
               const float* __restrict__ w_sp_d, const float* __restrict__ w_sp_s,
               const float* __restrict__ w_pow_s, const float* __restrict__ w_prop_s,
               float* __restrict__ out) {
    __shared__ float2 s_qc[R3][R3];   // (.x = dq = d/(c+eps), .y = c)
    __shared__ float2 s_t[R2][R2];    // (tc, ts)
    __shared__ float  s_s[R1][R1];    // s, 0 outside image
    __shared__ float  sw[20];         // wd[0..8], ws[9..17], wps, wpow

    // XCD-bijective swizzle: 2304 blocks = 8 XCDs x 288; each XCD gets a
    // contiguous 12x24-tile half-batch -> halo re-reads hit its private L2.
    const int orig = blockIdx.x;
    const int swz  = (orig & 7) * 288 + (orig >> 3);
    const int b    = swz / 576;
    const int rem  = swz - b * 576;
    const int ty0  = (rem / 24) * TS;
    const int tx0  = (rem % 24) * TS;

    const int tid = threadIdx.x;
    const float* dcd = x + b * PLANE;
    const float* cd  = x + (Bb + b) * PLANE;

    if (tid == 0) {   // inline weight prep
        float sd[9], ss[9], sum_d = 0.f, sum_s = 0.f;
        for (int r = 0; r < 3; ++r)
            for (int c = 0; c < 3; ++c) {
                int cc = (c == 2) ? 0 : c;      // mirrored 3rd column
                float vd = log1pf(expf(w_sp_d[r * 2 + cc]));
                float vs = log1pf(expf(w_sp_s[r * 2 + cc]));
                sd[r * 3 + c] = vd; ss[r * 3 + c] = vs;
                sum_d += vd; sum_s += vs;
            }
        for (int k = 0; k < 9; ++k) { sw[k] = sd[k] / sum_d; sw[9 + k] = ss[k] / sum_s; }
        sw[18] = 1.f / (1.f + expf(-w_prop_s[0]));   // wps
        sw[19] = log1pf(expf(w_pow_s[0]));           // wpow
    }

    // ---- Phase A: vectorized load at halo-3; dq precomputed once ----
    // Row covers gx in [tx0-4, tx0+36): 10 aligned float4 segments; only
    // seg 0 (left edge tile) and seg 9 (right edge tile) can go OOB.
    for (int it = tid; it < R3 * 10; it += 256) {
        int row = it / 10, seg = it - row * 10;
        int gy = ty0 - 3 + row;
        int gxb = tx0 - 4 + seg * 4;
        float4 vd4 = make_float4(0.f, 0.f, 0.f, 0.f);
        float4 vc4 = vd4;
        if ((unsigned)gy < (unsigned)Hh) {
            bool safe = (seg > 0 && seg < 9) || (seg == 0 ? (tx0 > 0) : (tx0 + TS < Ww));
            if (safe) {
                vd4 = *(const float4*)(dcd + gy * Ww + gxb);
                vc4 = *(const float4*)(cd  + gy * Ww + gxb);
            } else {
                if ((unsigned)(gxb + 0) < (unsigned)Ww) { vd4.x = dcd[gy*Ww+gxb+0]; vc4.x = cd[gy*Ww+gxb+0]; }
                if ((unsigned)(gxb + 1) < (unsigned)Ww) { vd4.y = dcd[gy*Ww+gxb+1]; vc4.y = cd[gy*Ww+gxb+1]; }
                if ((unsigned)(gxb + 2) < (unsigned)Ww) { vd4.z = dcd[gy*Ww+gxb+2]; vc4.z = cd[gy*Ww+gxb+2]; }
                if ((unsigned)(gxb + 3) < (unsigned)Ww) { vd4.w = dcd[gy*Ww+gxb+3]; vc4.w = cd[gy*Ww+gxb+3]; }
            }
        }
        int lxb = seg * 4 - 1;   // lx of component 0
        if ((unsigned)(lxb + 0) < (unsigned)R3) s_qc[row][lxb + 0] = make_float2(vd4.x / (vc4.x + EPSF), vc4.x);
        if ((unsigned)(lxb + 1) < (unsigned)R3) s_qc[row][lxb + 1] = make_float2(vd4.y / (vc4.y + EPSF), vc4.y);
        if ((unsigned)(lxb + 2) < (unsigned)R3) s_qc[row][lxb + 2] = make_float2(vd4.z / (vc4.z + EPSF), vc4.z);
        if ((unsigned)(lxb + 3) < (unsigned)R3) s_qc[row][lxb + 3] = make_float2(vd4.w / (vc4.w + EPSF), vc4.w);
    }

    // ---- Prefetch cs/scs for Phase B (hide HBM latency under barrier) ----
    const int xB = tid % R2;          // 0..35
    const int tyB = tid / R2;         // active < 6 (216 threads)
    const int yb0 = tyB * 6;
    float pcs[6], pscs[6];
    if (tyB < 6) {
        int gx = tx0 - 2 + xB;
        bool colok = (unsigned)gx < (unsigned)Ww;
        #pragma unroll
        for (int j = 0; j < 6; ++j) {
            int gy = ty0 - 2 + yb0 + j;
            bool ok = colok && (unsigned)gy < (unsigned)Hh;
            int idx = ok ? (b * PLANE + gy * Ww + gx) : 0;
            pcs[j]  = ok ? cs[idx]  : 0.f;
            pscs[j] = ok ? scs[idx] : 0.f;
        }
    }
    __syncthreads();

    const float wps  = sw[18];
    const float wpow = sw[19];
    const float onemw = 1.f - wps;

    // ---- Phase B: stage 1, column sweep (36 cols x 6 groups of 6 rows) ----
    // Hierarchical first-wins argmax: row-max over dx (k-minor), combine over
    // dy (k-major) — exactly reproduces jnp.argmax first-occurrence order.
    if (tyB < 6) {
        float ma[3], md[3], mc[3];    // jmax row-partials (key, dq, c)
        float nv[3], nq[3];           // jmin row-partials (vc, dq+eps)
#define HROW_B(rr, slot) { \
        float2 q0 = s_qc[rr][xB]; float2 q1 = s_qc[rr][xB + 1]; float2 q2 = s_qc[rr][xB + 2]; \
        float a0 = q0.x * q0.y, a1 = q1.x * q1.y, a2 = q2.x * q2.y; \
        float A = a0, D = q0.x, C = q0.y; \
        if (a1 > A) { A = a1; D = q1.x; C = q1.y; } \
        if (a2 > A) { A = a2; D = q2.x; C = q2.y; } \
        ma[slot] = A; md[slot] = D; mc[slot] = C; \
        float V = q0.y, Q = q0.x + EPSF; \
        float e1 = q1.x + EPSF, e2 = q2.x + EPSF; \
        if (q1.y * Q > V * e1) { V = q1.y; Q = e1; } \
        if (q2.y * Q > V * e2) { V = q2.y; Q = e2; } \
        nv[slot] = V; nq[slot] = Q; }
        HROW_B(yb0 + 0, 0)
        HROW_B(yb0 + 1, 1)
        #pragma unroll
        for (int j = 0; j < 6; ++j) {
            const int sl2 = (j + 2) % 3, s0 = j % 3, s1 = (j + 1) % 3;
            HROW_B(yb0 + j + 2, sl2)
            float A = ma[s0], D = md[s0], C = mc[s0];
            if (ma[s1]  > A) { A = ma[s1];  D = md[s1];  C = mc[s1];  }
            if (ma[sl2] > A) { A = ma[sl2]; D = md[sl2]; C = mc[sl2]; }
            float V = nv[s0], Q = nq[s0];
            if (nv[s1]  * Q > V * nq[s1])  { V = nv[s1];  Q = nq[s1];  }
            if (nv[sl2] * Q > V * nq[sl2]) { V = nv[sl2]; Q = nq[sl2]; }
            const int yb = yb0 + j;
            const int gy = ty0 - 2 + yb, gx = tx0 - 2 + xB;
            float tc = 0.f, ts = 0.f;
            if ((unsigned)gy < (unsigned)Hh && (unsigned)gx < (unsigned)Ww) {
                float s_new = __builtin_amdgcn_exp2f(wpow *
                    (__builtin_amdgcn_logf(Q) - __builtin_amdgcn_logf(D + EPSF)));
                float cs_new = C * V;
                tc = pcs[j]  * wps + cs_new * onemw;
                ts = pscs[j] * wps + s_new * cs_new * onemw;
            }
            s_t[yb][xB] = make_float2(tc, ts);
        }
    }
    __syncthreads();

    // ---- Phase C(a): interior conv, row-aligned mapping (32 rows x 8 col-groups)
    // Interior pixel (rC, cg+j) sits at halo-1 coord (rC+1, cg+1+j):
    // taps are s_t[rC+1+r][cg+1+j+kx] — row base rC+1, col window cg+1..cg+6.
    {
        const int rC = tid >> 3;            // interior row 0..31
        const int cg = (tid & 7) * 4;       // interior col base 0,4,..,28
        const float wa0 = sw[9],  wb0 = sw[10];
        const float wa1 = sw[12], wb1 = sw[13];
        const float wa2 = sw[15], wb2 = sw[16];
        float accC[4] = {0.f, 0.f, 0.f, 0.f};
        float accS[4] = {0.f, 0.f, 0.f, 0.f};
        #pragma unroll
        for (int r = 0; r < 3; ++r) {
            const float wa = (r == 0) ? wa0 : (r == 1) ? wa1 : wa2;
            const float wb = (r == 0) ? wb0 : (r == 1) ? wb1 : wb2;
            float2 t0 = s_t[rC + 1 + r][cg + 1];
            float2 t1 = s_t[rC + 1 + r][cg + 2];
            float2 t2 = s_t[rC + 1 + r][cg + 3];
            float2 t3 = s_t[rC + 1 + r][cg + 4];
            float2 t4 = s_t[rC + 1 + r][cg + 5];
            float2 t5 = s_t[rC + 1 + r][cg + 6];
            accC[0] += wa * (t0.x + t2.x) + wb * t1.x;
            accS[0] += wa * (t0.y + t2.y) + wb * t1.y;
            accC[1] += wa * (t1.x + t3.x) + wb * t2.x;
            accS[1] += wa * (t1.y + t3.y) + wb * t2.y;
            accC[2] += wa * (t2.x + t4.x) + wb * t3.x;
            accS[2] += wa * (t2.y + t4.y) + wb * t3.y;
            accC[3] += wa * (t3.x + t5.x) + wb * t4.x;
            accS[3] += wa * (t3.y + t5.y) + wb * t4.y;
        }
        #pragma unroll
        for (int j = 0; j < 4; ++j)
            s_s[rC + 1][cg + 1 + j] = accS[j] * __builtin_amdgcn_rcpf(accC[j] + EPSF);
        int idx = (ty0 + rC) * Ww + (tx0 + cg);
        *(float4*)(out + (8 + b)  * PLANE + idx) = make_float4(accS[0], accS[1], accS[2], accS[3]);
        *(float4*)(out + (12 + b) * PLANE + idx) = make_float4(accC[0], accC[1], accC[2], accC[3]);
    }
    // ---- Phase C(b): halo-1 ring (132 px), direct 9-tap; s=0 outside image
    if (tid < 132) {
        int yc, xC;
        if (tid < 34)       { yc = 0;  xC = tid; }
        else if (tid < 68)  { yc = 33; xC = tid - 34; }
        else if (tid < 100) { yc = 1 + (tid - 68);  xC = 0; }
        else                { yc = 1 + (tid - 100); xC = 33; }
        float aC = 0.f, aS = 0.f;
        #pragma unroll
        for (int k = 0; k < 9; ++k) {
            float2 t = s_t[yc + k / 3][xC + k % 3];
            aC += sw[9 + k] * t.x;
            aS += sw[9 + k] * t.y;
        }
        int gy = ty0 - 1 + yc, gx = tx0 - 1 + xC;
        bool in_img = (unsigned)gy < (unsigned)Hh && (unsigned)gx < (unsigned)Ww;
        s_s[yc][xC] = in_img ? (aS * __builtin_amdgcn_rcpf(aC + EPSF)) : 0.f;
    }
    __syncthreads();

    // ---- Phase D: stage 3, column sweep (32 cols x 8 groups of 4 rows) ----
    {
        const int xD = tid & 31, tyD = tid >> 5;
        const int yd0 = tyD * 4;
        float wdk[9];
        #pragma unroll
        for (int k = 0; k < 9; ++k) wdk[k] = sw[k];
        float  srw[3][3];
        float2 qrw[3][3];
#define HROW_D(rr, slot) { \
        srw[slot][0] = s_s[rr][xD]; srw[slot][1] = s_s[rr][xD + 1]; srw[slot][2] = s_s[rr][xD + 2]; \
        qrw[slot][0] = s_qc[rr + 2][xD + 2]; qrw[slot][1] = s_qc[rr + 2][xD + 3]; qrw[slot][2] = s_qc[rr + 2][xD + 4]; }
        HROW_D(yd0 + 0, 0)
        HROW_D(yd0 + 1, 1)
#define TAP_D(slot, kk, cc2) { \
        float wsk = ((kk) == 4) ? 1.f : (srw[slot][cc2] * sc); \
        float w = wdk[kk] * wsk; \
        float2 q = qrw[slot][cc2]; \
        acc_d += w * (q.x * (q.y + EPSF)); \
        acc_c += w * q.y; \
        acc_w += w; }
        #pragma unroll
        for (int j = 0; j < 4; ++j) {
            const int sl2 = (j + 2) % 3, s0 = j % 3, s1 = (j + 1) % 3;
            HROW_D(yd0 + j + 2, sl2)
            float sc = srw[s1][1];
            float acc_d = 0.f, acc_c = 0.f, acc_w = 0.f;
            TAP_D(s0, 0, 0) TAP_D(s0, 1, 1) TAP_D(s0, 2, 2)
            TAP_D(s1, 3, 0) TAP_D(s1, 4, 1) TAP_D(s1, 5, 2)
            TAP_D(sl2, 6, 0) TAP_D(sl2, 7, 1) TAP_D(sl2, 8, 2)
            float rinv = __builtin_amdgcn_rcpf(acc_w + EPSF);
            const int iy = yd0 + j;
            int idx = (ty0 + iy) * Ww + (tx0 + xD);
            out[(2 * b)     * PLANE + idx] = acc_d * rinv;   // x_out d-part
            out[(2 * b + 1) * PLANE + idx] = acc_c * rinv;   // x_out c-part
        }
    }
}

extern "C" void kernel_launch(void* const* d_in, const int* in_sizes, int n_in,
                              void* d_out, int out_size, void* d_ws, size_t ws_size,
                              hipStream_t stream) {
    const float* x        = (const float*)d_in[0];
    const float* scs      = (const float*)d_in[1];
    const float* cs       = (const float*)d_in[2];
    // d_in[3] = w_channel_d (1,1) -> normalizes to 1, unused
    const float* w_sp_d   = (const float*)d_in[4];
    const float* w_pow_s  = (const float*)d_in[5];
    const float* w_prop_s = (const float*)d_in[6];
    // d_in[7] = w_channel_s (1,1) -> normalizes to 1, unused
    const float* w_sp_s   = (const float*)d_in[8];
    float* out  = (float*)d_out;

    fused_all<<<dim3(24 * 24 * Bb), 256, 0, stream>>>(x, scs, cs, w_sp_d, w_sp_s,
                                                      w_pow_s, w_prop_s, out);
}